// Round 1
// 451.243 us; speedup vs baseline: 1.4839x; 1.4839x over previous
//
#include <hip/hip_runtime.h>

typedef __bf16 bf16x8 __attribute__((ext_vector_type(8)));
typedef float  f32x4  __attribute__((ext_vector_type(4)));

#define MFMA16(a,b,c) __builtin_amdgcn_mfma_f32_16x16x32_bf16((a),(b),(c),0,0,0)

constexpr int  HID  = 768;
constexpr long T    = 16384;          // NUM_SEQS * SEQ_LEN
constexpr long SZ   = T * HID;        // 12,582,912 elements
constexpr int  SEQ  = 2048;
constexpr int  NH   = 12;
constexpr int  HD   = 64;
constexpr int  WELE = HID * HID;      // 589,824

// Q pre-scale: (1/sqrt(64)) * log2(e)  -> softmax done in exp2 domain
constexpr float QSCALE = 0.125f * 1.4426950408889634f;
// log2(10000)/32 for RoPE inv_freq = 2^(-d * L10K32)
constexpr float L10K32 = 13.287712379549449f / 32.0f;

__device__ __forceinline__ unsigned pkbf(float a, float b) {
    union { __bf16 h[2]; unsigned u; } x;
    x.h[0] = (__bf16)a; x.h[1] = (__bf16)b; return x.u;
}

// async global->LDS, 16B per lane; LDS dest = uniform base + lane*16
__device__ __forceinline__ void gld16(const __bf16* g, __bf16* l) {
    __builtin_amdgcn_global_load_lds(
        (const __attribute__((address_space(1))) unsigned int*)g,
        (__attribute__((address_space(3))) unsigned int*)l, 16, 0, 0);
}

// ---------------------------------------------------------------------------
// Weight convert+transpose, LDS-tiled. Wt[n][k] = bf16(W[k][n]).
// ---------------------------------------------------------------------------
__global__ __launch_bounds__(256)
void wconv_kernel(const float* __restrict__ W0, __bf16* __restrict__ T0,
                  const float* __restrict__ W1, __bf16* __restrict__ T1,
                  const float* __restrict__ W2, __bf16* __restrict__ T2,
                  const float* __restrict__ W3, __bf16* __restrict__ T3) {
    const float* W; __bf16* Wt;
    switch (blockIdx.z) {
        case 0: W = W0; Wt = T0; break;
        case 1: W = W1; Wt = T1; break;
        case 2: W = W2; Wt = T2; break;
        default: W = W3; Wt = T3; break;
    }
    __shared__ float tile[64][65];
    int n0 = blockIdx.x * 64, k0 = blockIdx.y * 64;
    int c = threadIdx.x & 63, rr = threadIdx.x >> 6;
#pragma unroll
    for (int i = 0; i < 16; i++) {
        int r = i * 4 + rr;
        tile[r][c] = W[(long)(k0 + r) * HID + n0 + c];
    }
    __syncthreads();
#pragma unroll
    for (int i = 0; i < 16; i++) {
        int r = i * 4 + rr;
        Wt[(long)(n0 + r) * HID + k0 + c] = (__bf16)tile[c][r];
    }
}

// ---------------------------------------------------------------------------
// LayerNorm
// ---------------------------------------------------------------------------
__global__ __launch_bounds__(256)
void ln_kernel(const float* __restrict__ hs, const float* __restrict__ w,
               const float* __restrict__ b, __bf16* __restrict__ xbf) {
    int row = blockIdx.x, tid = threadIdx.x;
    const float* hr = hs + (long)row * HID;
    float v0 = hr[tid], v1 = hr[tid + 256], v2 = hr[tid + 512];
    float s  = v0 + v1 + v2;
    float s2 = v0 * v0 + v1 * v1 + v2 * v2;
#pragma unroll
    for (int off = 1; off < 64; off <<= 1) {
        s  += __shfl_xor(s, off);
        s2 += __shfl_xor(s2, off);
    }
    __shared__ float red[8];
    int wave = tid >> 6;
    if ((tid & 63) == 0) { red[wave] = s; red[4 + wave] = s2; }
    __syncthreads();
    s  = red[0] + red[1] + red[2] + red[3];
    s2 = red[4] + red[5] + red[6] + red[7];
    float mu   = s * (1.0f / HID);
    float var  = s2 * (1.0f / HID) - mu * mu;
    float rstd = rsqrtf(var + 1e-12f);
    long base = (long)row * HID;
    xbf[base + tid]       = (__bf16)((v0 - mu) * rstd * w[tid]       + b[tid]);
    xbf[base + tid + 256] = (__bf16)((v1 - mu) * rstd * w[tid + 256] + b[tid + 256]);
    xbf[base + tid + 512] = (__bf16)((v2 - mu) * rstd * w[tid + 512] + b[tid + 512]);
}

// ---------------------------------------------------------------------------
// GEMM, m97-style: C[M,N] = A[M,HID] @ Bt[N,HID]^T + bias.  (unchanged)
// ---------------------------------------------------------------------------
constexpr int SEGSZ = 528;   // elements per 8-row segment: 1024B data + 32B pad

template <int MODE>
__global__ __launch_bounds__(256)
void gemm_lds(const __bf16* __restrict__ A, const __bf16* __restrict__ Bt,
              const float* __restrict__ bias, __bf16* __restrict__ outb,
              const __bf16* __restrict__ resid, float* __restrict__ outf,
              float scale) {
    int tid = threadIdx.x, wave = tid >> 6, lane = tid & 63;
    int lr = lane & 15, quad = lane >> 4;
    int wm = wave >> 1, wn = wave & 1;
    long m0 = (long)blockIdx.x * 128;
    int  n0 = blockIdx.y * 128;

    __shared__ __align__(16) __bf16 As[16 * SEGSZ];
    __shared__ __align__(16) __bf16 Bs[16 * SEGSZ];

    const f32x4 vzero = {0.f, 0.f, 0.f, 0.f};
    f32x4 acc[4][4];
#pragma unroll
    for (int ms = 0; ms < 4; ms++)
#pragma unroll
        for (int ns = 0; ns < 4; ns++) acc[ms][ns] = vzero;

    const __bf16* ga = A  + (long)(m0 + wave * 32 + (lane >> 3)) * HID + (lane & 7) * 8;
    const __bf16* gb = Bt + (long)(n0 + wave * 32 + (lane >> 3)) * HID + (lane & 7) * 8;
    __bf16* la = As + wave * 4 * SEGSZ;
    __bf16* lb = Bs + wave * 4 * SEGSZ;

    int fbase = (lr >> 3) * SEGSZ + (lr & 7) * 64 + quad * 8;

    for (int k0 = 0; k0 < HID; k0 += 64) {
#pragma unroll
        for (int j = 0; j < 4; j++) {
            gld16(ga + (long)j * 8 * HID + k0, la + j * SEGSZ);
            gld16(gb + (long)j * 8 * HID + k0, lb + j * SEGSZ);
        }
        __syncthreads();
#pragma unroll
        for (int kk = 0; kk < 64; kk += 32) {
            bf16x8 af[4], bfr[4];
#pragma unroll
            for (int ms = 0; ms < 4; ms++)
                af[ms] = *(const bf16x8*)&As[fbase + (wm * 8 + ms * 2) * SEGSZ + kk];
#pragma unroll
            for (int ns = 0; ns < 4; ns++)
                bfr[ns] = *(const bf16x8*)&Bs[fbase + (wn * 8 + ns * 2) * SEGSZ + kk];
#pragma unroll
            for (int ms = 0; ms < 4; ms++)
#pragma unroll
                for (int ns = 0; ns < 4; ns++)
                    acc[ms][ns] = MFMA16(af[ms], bfr[ns], acc[ms][ns]);
        }
        __syncthreads();
    }

    if (MODE == 3) {
        int hb = n0 + wn * 64;
        float f1 = __builtin_amdgcn_exp2f(-(float)lr * L10K32);
        float f2 = __builtin_amdgcn_exp2f(-(float)(lr + 16) * L10K32);
        float b0 = bias[hb + lr],      b1 = bias[hb + 16 + lr];
        float b2 = bias[hb + 32 + lr], b3 = bias[hb + 48 + lr];
#pragma unroll
        for (int ms = 0; ms < 4; ms++)
#pragma unroll
        for (int r = 0; r < 4; r++) {
            long row = m0 + wm * 64 + ms * 16 + quad * 4 + r;
            int pos = (int)(row & (SEQ - 1));
            float s1, c1, s2, c2;
            __sincosf((float)pos * f1, &s1, &c1);
            __sincosf((float)pos * f2, &s2, &c2);
            float v0 = acc[ms][0][r] + b0, v1 = acc[ms][1][r] + b1;
            float v2 = acc[ms][2][r] + b2, v3 = acc[ms][3][r] + b3;
            __bf16* ob = outb + row * HID + hb;
            ob[lr]      = (__bf16)((v0 * c1 - v2 * s1) * scale);
            ob[16 + lr] = (__bf16)((v1 * c2 - v3 * s2) * scale);
            ob[32 + lr] = (__bf16)((v2 * c1 + v0 * s1) * scale);
            ob[48 + lr] = (__bf16)((v3 * c2 + v1 * s2) * scale);
        }
    } else if (MODE == 1) {
#pragma unroll
        for (int ms = 0; ms < 4; ms++)
#pragma unroll
        for (int r = 0; r < 4; r++) {
            int d = (int)(m0 + wm * 64 + ms * 16 + quad * 4 + r);   // 0..767
            float bv = bias[d];
            int hh = d >> 6, dd = d & 63;
#pragma unroll
            for (int ns = 0; ns < 4; ns++) {
                int posg = n0 + wn * 64 + ns * 16 + lr;
                int sq = posg >> 11, pos = posg & (SEQ - 1);
                outb[((long)((sq * NH + hh) * HD + dd) << 11) + pos] =
                    (__bf16)(acc[ms][ns][r] + bv);
            }
        }
    } else { // MODE 2
#pragma unroll
        for (int ns = 0; ns < 4; ns++) {
            int col = n0 + wn * 64 + ns * 16 + lr;
            float bv = bias[col];
#pragma unroll
            for (int ms = 0; ms < 4; ms++)
#pragma unroll
            for (int r = 0; r < 4; r++) {
                long row = m0 + wm * 64 + ms * 16 + quad * 4 + r;
                outf[row * HID + col] = acc[ms][ns][r] + bv + (float)resid[row * HID + col];
            }
        }
    }
}

// ---------------------------------------------------------------------------
// Flash attention, restructured:
//  * 1-D grid, XCD remap: s = b&7 (one sequence per XCD), qt fastest within
//    a head's 16 blocks -> K/V L2-resident per XCD.
//  * K (128x64) and V^T (64x128) tiles cooperatively staged into LDS via
//    global_load_lds, double-buffered: 2-phase pipeline
//    {STAGE(next); compute(cur); __syncthreads()} hides load latency and cuts
//    per-CU VMEM instructions 8x (waves no longer each re-load K/V).
//  * XOR swizzle chunk^=(row&7) applied on staging SOURCE and ds_read side
//    (linear LDS dest, rule: both-sides-or-neither) -> conflict-free b128.
//  * P buffer shrunk to per-g (32 keys): [4][32][40] = 10KB; total LDS 74KB
//    -> 2 blocks/CU.  Softmax math identical to previous version.
// ---------------------------------------------------------------------------
__global__ __launch_bounds__(256)
void attn_kernel(const __bf16* __restrict__ q, const __bf16* __restrict__ k,
                 const __bf16* __restrict__ vt, __bf16* __restrict__ att) {
    int tid = threadIdx.x, wave = tid >> 6, lane = tid & 63;
    int lr = lane & 15, quad = lane >> 4;
    int bb = blockIdx.x;
    int s  = bb & 7;           // sequence -> XCD (b%8 round-robin)
    int ii = bb >> 3;          // 0..191 within XCD
    int h  = ii >> 4;          // head 0..11
    int qt = ii & 15;          // q-tile, fastest within XCD
    long q0 = (long)s * SEQ + qt * 128 + wave * 32;

    __shared__ __align__(16) __bf16 Ks[2][128 * 64];   // 2 x 16KB
    __shared__ __align__(16) __bf16 Vs[2][64 * 128];   // 2 x 16KB
    __shared__ __align__(16) __bf16 Ps[4][32][40];     // 10KB (per-g P)

    const f32x4 vzero = {0.f, 0.f, 0.f, 0.f};

    bf16x8 qf[2][2];
#pragma unroll
    for (int m = 0; m < 2; m++) {
        const __bf16* qrow = q + (q0 + m * 16 + lr) * HID + h * HD + quad * 8;
        qf[m][0] = *(const bf16x8*)(qrow);
        qf[m][1] = *(const bf16x8*)(qrow + 32);
    }

    f32x4 o[2][4];
#pragma unroll
    for (int m = 0; m < 2; m++)
#pragma unroll
        for (int d = 0; d < 4; d++) o[m][d] = vzero;
    float m_i[2]  = {-INFINITY, -INFINITY};
    float lsum[2] = {0.f, 0.f};

    const __bf16* kg = k  + (long)s * SEQ * HID + h * HD;
    const __bf16* vg = vt + (long)(s * NH + h) * HD * SEQ;

    // Stage one 128-key tile: wave w loads K rows [w*32,w*32+32) (4 x 1KB)
    // and V rows [w*16,w*16+16) (4 x 1KB).  LDS dest linear; source chunk
    // pre-swizzled by ^(row&7) so swizzled ds_reads see the right data.
#define STAGE(bufi, kpos)                                                          \
    {                                                                              \
        _Pragma("unroll")                                                          \
        for (int j = 0; j < 4; j++) {                                              \
            int kr_ = wave * 32 + j * 8 + (lane >> 3);                             \
            gld16(kg + (long)((kpos) + kr_) * HID + (((lane & 7) ^ (kr_ & 7)) << 3), \
                  &Ks[bufi][(wave * 32 + j * 8) * 64]);                            \
            int vr_ = wave * 16 + j * 4 + (lane >> 4);                             \
            gld16(vg + (long)vr_ * SEQ + (kpos) + (((lane & 15) ^ (vr_ & 7)) << 3),  \
                  &Vs[bufi][(wave * 16 + j * 4) * 128]);                           \
        }                                                                          \
    }

    STAGE(0, 0)
    __syncthreads();

    for (int kt = 0; kt < SEQ / 128; kt++) {
        int cur = kt & 1;
        if (kt < SEQ / 128 - 1) STAGE(cur ^ 1, (kt + 1) * 128)

        // ---- QK^T from Ks (swizzled reads) ----
        f32x4 st[2][8];
#pragma unroll
        for (int jt = 0; jt < 8; jt++) {
            const __bf16* krow = &Ks[cur][(jt * 16 + lr) * 64];
            bf16x8 kf0 = *(const bf16x8*)&krow[((quad)     ^ (lr & 7)) << 3];
            bf16x8 kf1 = *(const bf16x8*)&krow[((4 + quad) ^ (lr & 7)) << 3];
#pragma unroll
            for (int m = 0; m < 2; m++) {
                f32x4 t0 = MFMA16(kf0, qf[m][0], vzero);
                st[m][jt] = MFMA16(kf1, qf[m][1], t0);
            }
        }

        // ---- online-softmax max/rescale ----
        float alpha[2];
#pragma unroll
        for (int m = 0; m < 2; m++) {
            f32x4 mx4 = st[m][0];
#pragma unroll
            for (int jt = 1; jt < 8; jt++) {
                mx4[0] = fmaxf(mx4[0], st[m][jt][0]);
                mx4[1] = fmaxf(mx4[1], st[m][jt][1]);
                mx4[2] = fmaxf(mx4[2], st[m][jt][2]);
                mx4[3] = fmaxf(mx4[3], st[m][jt][3]);
            }
            float mx = fmaxf(fmaxf(mx4[0], mx4[1]), fmaxf(mx4[2], mx4[3]));
            mx = fmaxf(mx, __shfl_xor(mx, 16));
            mx = fmaxf(mx, __shfl_xor(mx, 32));
            float nm = fmaxf(m_i[m], mx);
            alpha[m] = __builtin_amdgcn_exp2f(m_i[m] - nm);
            m_i[m] = nm;
            lsum[m] *= alpha[m];
#pragma unroll
            for (int d = 0; d < 4; d++) o[m][d] *= alpha[m];
        }

        // ---- per-g: exp + P write (32 keys) + PV from Vs ----
#pragma unroll
        for (int g = 0; g < 4; g++) {
#pragma unroll
            for (int m = 0; m < 2; m++) {
                float rs = 0.f;
#pragma unroll
                for (int jj = 0; jj < 2; jj++) {
                    int jt = g * 2 + jj;
                    float e0 = __builtin_amdgcn_exp2f(st[m][jt][0] - m_i[m]);
                    float e1 = __builtin_amdgcn_exp2f(st[m][jt][1] - m_i[m]);
                    float e2 = __builtin_amdgcn_exp2f(st[m][jt][2] - m_i[m]);
                    float e3 = __builtin_amdgcn_exp2f(st[m][jt][3] - m_i[m]);
                    rs += (e0 + e1) + (e2 + e3);
                    unsigned long long pw =
                        ((unsigned long long)pkbf(e2, e3) << 32) | pkbf(e0, e1);
                    *(unsigned long long*)&Ps[wave][m * 16 + lr][jj * 16 + quad * 4] = pw;
                }
                lsum[m] += rs;
            }
            asm volatile("s_waitcnt lgkmcnt(0)" ::: "memory");
            bf16x8 vf[4];
#pragma unroll
            for (int d = 0; d < 4; d++)
                vf[d] = *(const bf16x8*)
                    &Vs[cur][(d * 16 + lr) * 128 + (((g * 4 + quad) ^ (lr & 7)) << 3)];
#pragma unroll
            for (int m = 0; m < 2; m++) {
                bf16x8 pb = *(const bf16x8*)&Ps[wave][m * 16 + lr][quad * 8];
#pragma unroll
                for (int d = 0; d < 4; d++) o[m][d] = MFMA16(vf[d], pb, o[m][d]);
            }
        }
        __syncthreads();   // drains vmcnt(0): next tile staged; all reads done
    }
#undef STAGE

#pragma unroll
    for (int m = 0; m < 2; m++) {
        float l = lsum[m];
        l += __shfl_xor(l, 16);
        l += __shfl_xor(l, 32);
        float inv = 1.0f / l;
        long row = q0 + m * 16 + lr;
        __bf16* ob = att + row * HID + h * HD + quad * 4;
#pragma unroll
        for (int d = 0; d < 4; d++) {
            unsigned p0 = pkbf(o[m][d][0] * inv, o[m][d][1] * inv);
            unsigned p1 = pkbf(o[m][d][2] * inv, o[m][d][3] * inv);
            *(unsigned*)&ob[d * 16]     = p0;
            *(unsigned*)&ob[d * 16 + 2] = p1;
        }
    }
}

// ---------------------------------------------------------------------------
extern "C" void kernel_launch(void* const* d_in, const int* in_sizes, int n_in,
                              void* d_out, int out_size, void* d_ws, size_t ws_size,
                              hipStream_t stream) {
    const float* hs    = (const float*)d_in[0];
    const float* normw = (const float*)d_in[3];
    const float* normb = (const float*)d_in[4];
    const float* Wq = (const float*)d_in[5];
    const float* bq = (const float*)d_in[6];
    const float* Wk = (const float*)d_in[7];
    const float* bk = (const float*)d_in[8];
    const float* Wv = (const float*)d_in[9];
    const float* bv = (const float*)d_in[10];
    const float* Wo = (const float*)d_in[11];
    const float* bo = (const float*)d_in[12];

    __bf16* base = (__bf16*)d_ws;
    __bf16* x   = base;            // SZ
    __bf16* qb  = base + SZ;       // SZ
    __bf16* kb  = base + 2 * SZ;   // SZ
    __bf16* vtb = base + 3 * SZ;   // SZ  ([s][h][d][pos])
    __bf16* att = base + 4 * SZ;   // SZ
    __bf16* wqt = base + 5 * SZ;
    __bf16* wkt = wqt + WELE;
    __bf16* wvt = wkt + WELE;
    __bf16* wot = wvt + WELE;

    wconv_kernel<<<dim3(12, 12, 4), 256, 0, stream>>>(Wq, wqt, Wk, wkt, Wv, wvt, Wo, wot);

    ln_kernel<<<(int)T, 256, 0, stream>>>(hs, normw, normb, x);

    gemm_lds<3><<<dim3(T / 128, HID / 128), 256, 0, stream>>>(x, wqt, bq, qb, nullptr, nullptr, QSCALE);
    gemm_lds<3><<<dim3(T / 128, HID / 128), 256, 0, stream>>>(x, wkt, bk, kb, nullptr, nullptr, 1.0f);
    gemm_lds<1><<<dim3(HID / 128, T / 128), 256, 0, stream>>>(wvt, x, bv, vtb, nullptr, nullptr, 1.0f);

    attn_kernel<<<dim3(NH * 16 * 8), 256, 0, stream>>>(qb, kb, vtb, att);

    gemm_lds<2><<<dim3(T / 128, HID / 128), 256, 0, stream>>>(att, wot, bo, nullptr, x, (float*)d_out, 1.0f);
}